// Round 3
// baseline (4296.914 us; speedup 1.0000x reference)
//
#include <hip/hip_runtime.h>
#include <math.h>

#define NN   50000      // nodes per type
#define NTOT 100000
#define FD   256        // hidden dim
#define EC   150000     // edges per edge type

static const size_t NF = (size_t)NN * FD;   // 12.8M floats

__device__ __forceinline__ float gelu_f(float x) {
  return 0.5f * x * (1.0f + erff(x * 0.7071067811865475f));
}
__device__ __forceinline__ unsigned short f2bf(float x) {   // RTN f32->bf16
  unsigned u = __float_as_uint(x);
  u += 0x7FFFu + ((u >> 16) & 1u);
  return (unsigned short)(u >> 16);
}
__device__ __forceinline__ float bf2f(unsigned short u) {
  return __uint_as_float((unsigned)u << 16);
}

// ---------------------------------------------------------------------------
// Generic f32 GEMM: C = [gelu?](act(A) @ B + bias), optional in-place skip,
// optional bf16 output. A:[M,K] lda, B:[K,N] ldb. 128x128x16 tiles, 256 thr.
// NOTE: C and Xs may alias (in-place skip) -> no __restrict__ on them.
// ---------------------------------------------------------------------------
template<int GELU_A, int SKIP_EP, int GELU_C, int OUT_BF16>
__global__ __launch_bounds__(256) void gemm_f32(
    const float* __restrict__ A, int lda,
    const float* __restrict__ B, int ldb,
    const float* __restrict__ bias,
    void* Cv, int ldc,
    const float* Xs,                  // skip input [M,ldc] (may alias C)
    const float* __restrict__ skipp,  // raw skip scalar
    int M, int N, int K)
{
  __shared__ float As[16][128];
  __shared__ float Bs[16][128];
  const int bm = blockIdx.y * 128;
  const int bn = blockIdx.x * 128;
  const int tid = threadIdx.x;
  const int tx = tid & 15, ty = tid >> 4;
  const int arow = tid >> 1, acg = (tid & 1) * 8;
  const int brow = tid >> 4, bcg = (tid & 15) * 8;
  const bool avalid = (bm + arow) < M;
  const float* aptr = A + (size_t)(bm + arow) * lda + acg;
  const float* bptr = B + (size_t)brow * ldb + bn + bcg;
  float acc[8][8] = {};

  for (int k0 = 0; k0 < K; k0 += 16) {
    float4 av0 = make_float4(0.f,0.f,0.f,0.f), av1 = make_float4(0.f,0.f,0.f,0.f);
    if (avalid) {
      av0 = *(const float4*)(aptr + k0);
      av1 = *(const float4*)(aptr + k0 + 4);
    }
    if (GELU_A) {
      av0.x = gelu_f(av0.x); av0.y = gelu_f(av0.y); av0.z = gelu_f(av0.z); av0.w = gelu_f(av0.w);
      av1.x = gelu_f(av1.x); av1.y = gelu_f(av1.y); av1.z = gelu_f(av1.z); av1.w = gelu_f(av1.w);
    }
    float4 bv0 = *(const float4*)(bptr + (size_t)k0 * ldb);
    float4 bv1 = *(const float4*)(bptr + (size_t)k0 * ldb + 4);
    As[acg+0][arow] = av0.x; As[acg+1][arow] = av0.y;
    As[acg+2][arow] = av0.z; As[acg+3][arow] = av0.w;
    As[acg+4][arow] = av1.x; As[acg+5][arow] = av1.y;
    As[acg+6][arow] = av1.z; As[acg+7][arow] = av1.w;
    *(float4*)&Bs[brow][bcg]     = bv0;
    *(float4*)&Bs[brow][bcg + 4] = bv1;
    __syncthreads();
    #pragma unroll
    for (int kk = 0; kk < 16; kk++) {
      float4 a0 = *(const float4*)&As[kk][ty*4];
      float4 a1 = *(const float4*)&As[kk][64 + ty*4];
      float4 b0 = *(const float4*)&Bs[kk][tx*4];
      float4 b1 = *(const float4*)&Bs[kk][64 + tx*4];
      float a[8] = {a0.x,a0.y,a0.z,a0.w,a1.x,a1.y,a1.z,a1.w};
      float b[8] = {b0.x,b0.y,b0.z,b0.w,b1.x,b1.y,b1.z,b1.w};
      #pragma unroll
      for (int i = 0; i < 8; i++)
        #pragma unroll
        for (int j = 0; j < 8; j++)
          acc[i][j] = fmaf(a[i], b[j], acc[i][j]);
    }
    __syncthreads();
  }

  float sg = 0.f;
  if (SKIP_EP) sg = 1.f / (1.f + expf(-skipp[0]));
  #pragma unroll
  for (int i = 0; i < 8; i++) {
    int rr = (i < 4) ? (ty*4 + i) : (64 + ty*4 + i - 4);
    int r = bm + rr;
    if (r >= M) continue;
    #pragma unroll
    for (int half = 0; half < 2; half++) {
      int c0 = bn + half*64 + tx*4;
      float v[4];
      #pragma unroll
      for (int j = 0; j < 4; j++) {
        float x = acc[i][half*4 + j] + bias[c0 + j];
        if (GELU_C) x = gelu_f(x);
        v[j] = x;
      }
      if (SKIP_EP) {
        float4 xs = *(const float4*)&Xs[(size_t)r * ldc + c0];
        v[0] = sg*v[0] + (1.f-sg)*xs.x;
        v[1] = sg*v[1] + (1.f-sg)*xs.y;
        v[2] = sg*v[2] + (1.f-sg)*xs.z;
        v[3] = sg*v[3] + (1.f-sg)*xs.w;
      }
      if (OUT_BF16) {
        ushort4 o;
        o.x = f2bf(v[0]); o.y = f2bf(v[1]); o.z = f2bf(v[2]); o.w = f2bf(v[3]);
        *(ushort4*)&((unsigned short*)Cv)[(size_t)r * ldc + c0] = o;
      } else {
        float4 o = make_float4(v[0], v[1], v[2], v[3]);
        *(float4*)&((float*)Cv)[(size_t)r * ldc + c0] = o;
      }
    }
  }
}

// ---------------------------------------------------------------------------
// Combined weights: Wc[z=et*2+kv][256,256] = Wkqv_block(st,h) @ Wrel[h,et],
// prel/sqrt(D) folded into k-side. grid (6,8), block 256.
// ---------------------------------------------------------------------------
__global__ __launch_bounds__(256) void wcomb_kernel(
    const float* __restrict__ Wkqv, const float* __restrict__ bkqv,
    const float* __restrict__ Wkrel, const float* __restrict__ Wvrel,
    const float* __restrict__ prel,
    float* __restrict__ Wc, float* __restrict__ bc)
{
  const int z = blockIdx.x, et = z >> 1, kv = z & 1;
  const int h = blockIdx.y;
  const int st = (et == 1) ? 1 : 0;
  const int cbase = (kv ? 512 : 0) + h * 32;
  const float scale = kv ? 1.0f : (prel[et*8 + h] * 0.1767766952966369f);
  __shared__ float Wr[32][32];
  const int tid = threadIdx.x;
  {
    const float* wr = (kv ? Wvrel : Wkrel) + ((size_t)(h*3 + et)) * 1024;
    for (int i = tid; i < 1024; i += 256) Wr[i >> 5][i & 31] = wr[i];
  }
  __syncthreads();
  const float* w1 = Wkqv + (size_t)st * 196608 + (size_t)tid * 768 + cbase;
  float acc[32] = {};
  for (int d = 0; d < 32; d++) {
    float v = w1[d];
    #pragma unroll
    for (int j = 0; j < 32; j++) acc[j] = fmaf(v, Wr[d][j], acc[j]);
  }
  float* outp = Wc + (size_t)z * 65536 + (size_t)tid * 256 + h * 32;
  for (int j = 0; j < 32; j++) outp[j] = acc[j] * scale;
  if (tid < 32) {
    const float* bk = bkqv + st * 768 + cbase;
    float a = 0.f;
    for (int d = 0; d < 32; d++) a = fmaf(bk[d], Wr[d][tid], a);
    bc[z * 256 + h * 32 + tid] = a * scale;
  }
}

// ---------------------------------------------------------------------------
// Union-CSR attention for one dst type: one wave per dst node, online softmax
// over all in-edges, agg written OVER the Q row (each row owned by one wave).
// ---------------------------------------------------------------------------
__global__ __launch_bounds__(256) void attn_union(
    float* qagg,                                  // [NN,256]: Q in, agg out
    const unsigned short* __restrict__ KEu,       // [2NN,256] bf16
    const unsigned short* __restrict__ VEu,       // [2NN,256] bf16
    const int* __restrict__ indptr, const int* __restrict__ adj)
{
  const int wid = (int)(((size_t)blockIdx.x * 256 + threadIdx.x) >> 6);
  if (wid >= NN) return;
  const int lane = threadIdx.x & 63;
  const int off = lane * 4;      // == h*32 + lh*4 for h=lane>>3, lh=lane&7
  const float4 q4 = *(const float4*)(qagg + (size_t)wid * FD + off);
  float m = -INFINITY, s = 0.f, ax = 0.f, ay = 0.f, az = 0.f, aw = 0.f;
  const int beg = indptr[wid], end = indptr[wid + 1];
  for (int i = beg; i < end; i++) {
    const int src = adj[i];     // global src id in [0, 2*NN)
    ushort4 ku = *(const ushort4*)(KEu + (size_t)src * FD + off);
    float d = q4.x*bf2f(ku.x) + q4.y*bf2f(ku.y) + q4.z*bf2f(ku.z) + q4.w*bf2f(ku.w);
    d += __shfl_xor(d, 1); d += __shfl_xor(d, 2); d += __shfl_xor(d, 4);
    float mn = fmaxf(m, d);
    float sc = expf(m - mn);    // m=-inf on first edge -> 0
    float w  = expf(d - mn);
    s = s * sc + w;
    ushort4 vu = *(const ushort4*)(VEu + (size_t)src * FD + off);
    ax = ax*sc + w*bf2f(vu.x); ay = ay*sc + w*bf2f(vu.y);
    az = az*sc + w*bf2f(vu.z); aw = aw*sc + w*bf2f(vu.w);
    m = mn;
  }
  const float inv = 1.f / (s + 1e-16f);
  *(float4*)(qagg + (size_t)wid * FD + off) = make_float4(ax*inv, ay*inv, az*inv, aw*inv);
}

// ---------------------------------------------------------------------------
__global__ __launch_bounds__(256) void ln_gelu_kernel(
    float* __restrict__ x, const float* __restrict__ g, const float* __restrict__ b)
{
  const int wid = (int)(((size_t)blockIdx.x * 256 + threadIdx.x) >> 6);
  if (wid >= NTOT) return;
  const int lane = threadIdx.x & 63;
  const int t = (wid >= NN) ? 1 : 0;   // rows [0,NN)=op, [NN,2NN)=var
  float4 v = *(float4*)(x + (size_t)wid * FD + lane*4);
  float sum = v.x + v.y + v.z + v.w;
  #pragma unroll
  for (int o = 1; o < 64; o <<= 1) sum += __shfl_xor(sum, o);
  float mu = sum * (1.f/256.f);
  float dx = v.x-mu, dy = v.y-mu, dz = v.z-mu, dw = v.w-mu;
  float vs = dx*dx + dy*dy + dz*dz + dw*dw;
  #pragma unroll
  for (int o = 1; o < 64; o <<= 1) vs += __shfl_xor(vs, o);
  float var = vs * (1.f/256.f);
  float rs = 1.f / sqrtf(var + 1e-5f);
  int c = lane*4;
  float4 gv = *(const float4*)(g + t*FD + c);
  float4 bv = *(const float4*)(b + t*FD + c);
  float y0 = dx*rs*gv.x + bv.x, y1 = dy*rs*gv.y + bv.y;
  float y2 = dz*rs*gv.z + bv.z, y3 = dw*rs*gv.w + bv.w;
  float4 o4 = make_float4(gelu_f(y0), gelu_f(y1), gelu_f(y2), gelu_f(y3));
  *(float4*)(x + (size_t)wid * FD + c) = o4;
}

__global__ __launch_bounds__(256) void gelu_kernel(float* __restrict__ x, size_t n4)
{
  size_t i = ((size_t)blockIdx.x * 256 + threadIdx.x);
  if (i >= n4) return;
  float4 v = *(float4*)(x + i*4);
  v.x = gelu_f(v.x); v.y = gelu_f(v.y); v.z = gelu_f(v.z); v.w = gelu_f(v.w);
  *(float4*)(x + i*4) = v;
}

// ---------------------------------------------------------------------------
// CSR build: var-dst CSR (from e0) and op-dst union CSR (from e1+e2).
// adj stores GLOBAL src id: op src = id, var src = NN+id.
// ---------------------------------------------------------------------------
__global__ __launch_bounds__(256) void count_v(const int* __restrict__ e0,
                                               int* __restrict__ degv) {
  int i = blockIdx.x * 256 + threadIdx.x;
  if (i >= EC) return;
  atomicAdd(&degv[e0[EC + i]], 1);
}
__global__ __launch_bounds__(256) void count_o(const int* __restrict__ e1,
                                               const int* __restrict__ e2,
                                               int* __restrict__ dego) {
  int i = blockIdx.x * 256 + threadIdx.x;
  if (i >= 2*EC) return;
  int dst = (i < EC) ? e1[EC + i] : e2[EC + (i - EC)];
  atomicAdd(&dego[dst], 1);
}

__global__ __launch_bounds__(1024) void scan_n(
    const int* __restrict__ deg, int* __restrict__ indptr,
    int* __restrict__ cursor, int n)
{
  __shared__ int ts[1024];
  const int tid = threadIdx.x;
  const int per = (n + 1023) / 1024;
  int s0 = tid * per, s1 = s0 + per; if (s1 > n) s1 = n; if (s0 > n) s0 = n;
  int loc = 0;
  for (int i = s0; i < s1; i++) loc += deg[i];
  ts[tid] = loc;
  __syncthreads();
  for (int off = 1; off < 1024; off <<= 1) {
    int v = (tid >= off) ? ts[tid - off] : 0;
    __syncthreads();
    ts[tid] += v;
    __syncthreads();
  }
  int base = (tid == 0) ? 0 : ts[tid - 1];
  for (int i = s0; i < s1; i++) {
    indptr[i] = base; cursor[i] = base; base += deg[i];
  }
  if (tid == 0) indptr[n] = ts[1023];
}

__global__ __launch_bounds__(256) void scat_v(const int* __restrict__ e0,
                                              int* __restrict__ cv,
                                              int* __restrict__ adjv) {
  int i = blockIdx.x * 256 + threadIdx.x;
  if (i >= EC) return;
  int pos = atomicAdd(&cv[e0[EC + i]], 1);
  adjv[pos] = e0[i];                      // src is op type -> global id
}
__global__ __launch_bounds__(256) void scat_o(const int* __restrict__ e1,
                                              const int* __restrict__ e2,
                                              int* __restrict__ co,
                                              int* __restrict__ adjo) {
  int i = blockIdx.x * 256 + threadIdx.x;
  if (i >= 2*EC) return;
  int dst, srcg;
  if (i < EC) { dst = e1[EC + i]; srcg = NN + e1[i]; }      // et1: var src
  else        { int j = i - EC; dst = e2[EC + j]; srcg = e2[j]; } // et2: op src
  int pos = atomicAdd(&co[dst], 1);
  adjo[pos] = srcg;
}

// ---------------------------------------------------------------------------
__global__ __launch_bounds__(256) void colmean_kernel(
    const float* __restrict__ gmat, double* __restrict__ outp, int n)
{
  const int c = threadIdx.x;
  const int r0 = blockIdx.x * 256;
  int rend = r0 + 256; if (rend > n) rend = n;
  double sum = 0.0;
  for (int r = r0; r < rend; r++) sum += (double)gmat[(size_t)r * FD + c];
  atomicAdd(&outp[c], sum);
}

__global__ __launch_bounds__(256) void head_kernel(
    const double* __restrict__ meand,
    const float* __restrict__ Wagg2, const float* __restrict__ bagg2,
    const float* __restrict__ Wo, const float* __restrict__ bo,
    float* __restrict__ outp)
{
  __shared__ float mv[256];
  __shared__ float h2[128];
  const int tid = threadIdx.x;
  mv[tid] = (float)(meand[tid] * (1.0 / (double)NTOT));
  __syncthreads();
  if (tid < 128) {
    float acc = bagg2[tid];
    for (int k = 0; k < 256; k++) acc = fmaf(mv[k], Wagg2[k*128 + tid], acc);
    h2[tid] = gelu_f(acc);
  }
  __syncthreads();
  if (tid < 16) {
    float acc = bo[tid];
    for (int k = 0; k < 128; k++) acc = fmaf(h2[k], Wo[k*16 + tid], acc);
    if (isnan(acc)) acc = 0.f;
    else if (isinf(acc)) acc = (acc > 0.f) ? 3.4028234663852886e38f : -3.4028234663852886e38f;
    outp[tid] = acc;
  }
}

__global__ void fill_kernel(float* p, int n, float v) {
  int i = blockIdx.x * 64 + threadIdx.x;
  if (i < n) p[i] = v;
}

// ---------------------------------------------------------------------------
extern "C" void kernel_launch(void* const* d_in, const int* in_sizes, int n_in,
                              void* d_out, int out_size, void* d_ws, size_t ws_size,
                              hipStream_t stream)
{
  const float* x_op_in  = (const float*)d_in[0];
  const float* x_var_in = (const float*)d_in[1];
  struct LayerP { const float *Wkqv,*bkqv,*Wkrel,*Wvrel,*prel,*Wout,*bout,*skip; };
  LayerP L[3];
  for (int i = 0; i < 3; i++) {
    int b = 2 + i*8;
    L[i].Wkqv  = (const float*)d_in[b+0];
    L[i].bkqv  = (const float*)d_in[b+1];
    L[i].Wkrel = (const float*)d_in[b+2];
    L[i].Wvrel = (const float*)d_in[b+3];
    L[i].prel  = (const float*)d_in[b+4];
    L[i].Wout  = (const float*)d_in[b+5];
    L[i].bout  = (const float*)d_in[b+6];
    L[i].skip  = (const float*)d_in[b+7];
  }
  const float* ln_g  = (const float*)d_in[26];
  const float* ln_b  = (const float*)d_in[27];
  const float* Wagg1 = (const float*)d_in[28];
  const float* bagg1 = (const float*)d_in[29];
  const float* Wagg2 = (const float*)d_in[30];
  const float* bagg2 = (const float*)d_in[31];
  const float* Wo    = (const float*)d_in[32];
  const float* bo    = (const float*)d_in[33];
  const int* e0 = (const int*)d_in[34];   // op -> var
  const int* e1 = (const int*)d_in[35];   // var -> op
  const int* e2 = (const int*)d_in[36];   // op -> op

  // ---- workspace layout (~260.6 MB decimal, fits 256 MiB) ----
  float* X    = (float*)d_ws;               // [0,2NF): op rows then var rows
  float* Xop  = X;
  float* Xvar = X + NF;
  float* Qb   = X + 2*NF;                   // [2NF,3NF): Q / agg (aliased)
  unsigned short* KEu = (unsigned short*)(X + 3*NF);  // [2NN,256] bf16
  unsigned short* VEu = (unsigned short*)(X + 4*NF);  // [2NN,256] bf16
  float* Wc   = X + 5*NF;                   // 6*65536
  float* bc   = Wc + 6*65536;               // 1536
  double* meand = (double*)(bc + 1536);     // 256 doubles
  int* ipv  = (int*)(meand + 256);          // NN+1
  int* ipo  = ipv + (NN + 1);               // NN+1
  int* cv   = ipo + (NN + 1);               // NN
  int* co   = cv + NN;                      // NN
  int* degv = co + NN;                      // NN
  int* dego = degv + NN;                    // NN
  int* adjv = dego + NN;                    // EC
  int* adjo = adjv + EC;                    // 2*EC
  size_t need = (size_t)((char*)(adjo + 2*EC) - (char*)d_ws);
  if (ws_size < need) {   // sentinel encodes ws_size in MiB*1000
    float v = (float)(ws_size >> 20) * 1000.0f;
    fill_kernel<<<dim3((out_size + 63)/64), 64, 0, stream>>>((float*)d_out, out_size, v);
    return;
  }

  // ---- CSR build (edges constant across layers) ----
  hipMemsetAsync(degv, 0, 2*NN*sizeof(int), stream);   // degv+dego contiguous
  hipMemsetAsync(meand, 0, 256*sizeof(double), stream);
  count_v<<<dim3((EC + 255)/256), 256, 0, stream>>>(e0, degv);
  count_o<<<dim3((2*EC + 255)/256), 256, 0, stream>>>(e1, e2, dego);
  scan_n<<<dim3(1), 1024, 0, stream>>>(degv, ipv, cv, NN);
  scan_n<<<dim3(1), 1024, 0, stream>>>(dego, ipo, co, NN);
  scat_v<<<dim3((EC + 255)/256), 256, 0, stream>>>(e0, cv, adjv);
  scat_o<<<dim3((2*EC + 255)/256), 256, 0, stream>>>(e1, e2, co, adjo);

  const dim3 g2(2, 391);                       // [50000 x 256] GEMM grid
  const dim3 ga((NN*64 + 255)/256);            // attention grid (1 wave/node)

  for (int layer = 0; layer < 3; layer++) {
    const LayerP& P = L[layer];
    const float* xo = layer ? Xop  : x_op_in;
    const float* xv = layer ? Xvar : x_var_in;

    wcomb_kernel<<<dim3(6, 8), 256, 0, stream>>>(P.Wkqv, P.bkqv, P.Wkrel, P.Wvrel,
                                                 P.prel, Wc, bc);
    // ---- VAR-dst phase (et0: op -> var) ----
    gemm_f32<0,0,0,0><<<g2, 256, 0, stream>>>(            // Q_var
        xv, FD, P.Wkqv + 196608 + 256, 768, P.bkqv + 768 + 256,
        Qb, FD, nullptr, nullptr, NN, 256, 256);
    gemm_f32<0,0,0,1><<<g2, 256, 0, stream>>>(            // KE0 -> rows [0,NN)
        xo, FD, Wc + 0*65536, 256, bc + 0*256, KEu, FD, nullptr, nullptr, NN, 256, 256);
    gemm_f32<0,0,0,1><<<g2, 256, 0, stream>>>(            // VE0
        xo, FD, Wc + 1*65536, 256, bc + 1*256, VEu, FD, nullptr, nullptr, NN, 256, 256);
    attn_union<<<ga, 256, 0, stream>>>(Qb, KEu, VEu, ipv, adjv);

    // op-phase projections of x_var BEFORE overwriting it
    gemm_f32<0,0,0,1><<<g2, 256, 0, stream>>>(            // KE1 -> rows [NN,2NN)
        xv, FD, Wc + 2*65536, 256, bc + 2*256, KEu + NF, FD, nullptr, nullptr, NN, 256, 256);
    gemm_f32<0,0,0,1><<<g2, 256, 0, stream>>>(            // VE1
        xv, FD, Wc + 3*65536, 256, bc + 3*256, VEu + NF, FD, nullptr, nullptr, NN, 256, 256);
    gemm_f32<1,1,0,0><<<g2, 256, 0, stream>>>(            // Wout var (in-place ok)
        Qb, FD, P.Wout + 65536, 256, P.bout + 256,
        Xvar, FD, xv, P.skip + 1, NN, 256, 256);

    // ---- OP-dst phase (et1: var->op, et2: op->op) ----
    gemm_f32<0,0,0,1><<<g2, 256, 0, stream>>>(            // KE2 -> rows [0,NN)
        xo, FD, Wc + 4*65536, 256, bc + 4*256, KEu, FD, nullptr, nullptr, NN, 256, 256);
    gemm_f32<0,0,0,1><<<g2, 256, 0, stream>>>(            // VE2
        xo, FD, Wc + 5*65536, 256, bc + 5*256, VEu, FD, nullptr, nullptr, NN, 256, 256);
    gemm_f32<0,0,0,0><<<g2, 256, 0, stream>>>(            // Q_op
        xo, FD, P.Wkqv + 256, 768, P.bkqv + 256,
        Qb, FD, nullptr, nullptr, NN, 256, 256);
    attn_union<<<ga, 256, 0, stream>>>(Qb, KEu, VEu, ipo, adjo);
    gemm_f32<1,1,0,0><<<g2, 256, 0, stream>>>(            // Wout op (in-place ok)
        Qb, FD, P.Wout, 256, P.bout,
        Xop, FD, xo, P.skip + 0, NN, 256, 256);

    // ---- inter-layer elementwise on contiguous 2NF ----
    if (layer == 0)
      ln_gelu_kernel<<<dim3((NTOT*64 + 255)/256), 256, 0, stream>>>(X, ln_g, ln_b);
    else
      gelu_kernel<<<dim3((int)(2*NF/4 + 255)/256), 256, 0, stream>>>(X, 2*NF/4);
  }

  // ---- final head: gelu(h @ Wagg1 + b) -> column mean (f64) -> MLP ----
  gemm_f32<0,0,1,0><<<g2, 256, 0, stream>>>(
      Xop, FD, Wagg1, 256, bagg1, Qb, FD, nullptr, nullptr, NN, 256, 256);
  colmean_kernel<<<dim3((NN + 255)/256), 256, 0, stream>>>(Qb, meand, NN);
  gemm_f32<0,0,1,0><<<g2, 256, 0, stream>>>(
      Xvar, FD, Wagg1 + 65536, 256, bagg1 + 256, Qb, FD, nullptr, nullptr, NN, 256, 256);
  colmean_kernel<<<dim3((NN + 255)/256), 256, 0, stream>>>(Qb, meand, NN);
  head_kernel<<<dim3(1), 256, 0, stream>>>(meand, Wagg2, bagg2, Wo, bo, (float*)d_out);
}